// Round 5
// baseline (166.166 us; speedup 1.0000x reference)
//
#include <hip/hip_runtime.h>

#define K_CLUSTERS 512
#define D_FEAT 64
#define ROWS_PER_BLOCK 32
#define THREADS 256

typedef short bf16x8 __attribute__((ext_vector_type(8)));
typedef short bf16x4 __attribute__((ext_vector_type(4)));
typedef float f32x4 __attribute__((ext_vector_type(4)));

__device__ __forceinline__ unsigned short f32_to_bf16(float f) {
  unsigned int u = __float_as_uint(f);
  u += 0x7fffu + ((u >> 16) & 1u);   // RNE
  return (unsigned short)(u >> 16);
}
__device__ __forceinline__ float bf16_to_f32(unsigned short h) {
  return __uint_as_float(((unsigned int)h) << 16);
}

// W swizzle v3: element index xor ((row>>1)&7)<<3.
// - Phase-A b16 scatter writes: one instr covers rows {rt*16 + q*4 + r}, q=0..3
//   -> keys (2q + (r>>1)) & 7 are distinct per quad -> the 4 quads land in 4
//   disjoint bank windows; within a window 16 b16 elems = 8 banks x 2 -> ~free.
// - Phase-C b128 reads: 16 lanes (16 rows) per quad, keys pair up -> 8 chunks
//   x 2 lanes = 32 banks at 2 lanes/bank (free per m136).
#define WSWZ(row) (((((unsigned)(row)) >> 1) & 7u) << 3)

// ---------------- prep: one wave per cluster, lane = feature. Coalesced.
__global__ void kmeans_prep(const float* __restrict__ cent,
                            unsigned short* __restrict__ chi,   // [K][D]
                            unsigned short* __restrict__ clo,   // [K][D]
                            unsigned short* __restrict__ cthi,  // [D][K]
                            float* __restrict__ csqs) {         // [K], 10*log2e*|c|^2
  const int wv = threadIdx.x >> 6;
  const int lane = threadIdx.x & 63;
  const int k = blockIdx.x * 4 + wv;    // grid = 128 blocks -> k in [0,512)
  const int f = lane;
  float v = cent[k * D_FEAT + f];
  unsigned short h = f32_to_bf16(v);
  float rem = v - bf16_to_f32(h);
  unsigned short l = f32_to_bf16(rem);
  chi[k * D_FEAT + f] = h;
  clo[k * D_FEAT + f] = l;
  cthi[f * K_CLUSTERS + k] = h;
  float s = v * v;
#pragma unroll
  for (int d = 1; d < 64; d <<= 1) s += __shfl_xor(s, d, 64);
  if (lane == 0) csqs[k] = s * 14.42695040888963f;  // 10 * log2(e)
}

// ---------------- main fused kernel: 32 rows/block, 4 blocks/CU.
// Phase A: cluster-split (wave owns 128 clusters, 2 row-tiles), depth-2
// prefetch, weights exp'd + streamed to swizzled LDS (no max pass: logits
// bounded in exp2 domain).
// Phase C: feature-split (wave owns 16 feats), W from LDS, hi-centroids only
// (convex combination -> bf16 c rounding adds <~5e-4, within threshold).
__global__ __launch_bounds__(THREADS, 4) void kmeans_main(
    const float* __restrict__ x,
    const unsigned short* __restrict__ chi,
    const unsigned short* __restrict__ clo,
    const unsigned short* __restrict__ cthi,
    const float* __restrict__ csqs,
    float* __restrict__ out) {
  // LDS: W [32][512] bf16 (32768 B, swizzled) + redsum [32][4] f32 (512 B).
  // x staging xh/xl [32][72] (9216 B) aliases head of W (dead after A-frag
  // loads, fenced by barrier 2). Total 33280 B -> 4 blocks/CU.
  __shared__ __attribute__((aligned(16))) unsigned char smem[32768 + 512];
  unsigned short* xh = (unsigned short*)smem;            // [32][72]
  unsigned short* xl = xh + 32 * 72;                     // [32][72]
  unsigned short* W  = (unsigned short*)smem;            // [32][512] swizzled
  float* redsum = (float*)(smem + 32768);                // [32][4]

  const int tid  = threadIdx.x;
  const int wv   = tid >> 6;
  const int lane = tid & 63;
  const int l16  = lane & 15;
  const int quad = lane >> 4;
  const long long rowbase = (long long)blockIdx.x * ROWS_PER_BLOCK;

  // ---- stage x -> xh/xl (coalesced float4 loads, hi/lo bf16 split) ----
  {
    int r  = tid >> 3;             // 0..31
    int f0 = (tid & 7) * 8;        // 0..56
    const float4* src4 = (const float4*)(x + (rowbase + r) * D_FEAT + f0);
#pragma unroll
    for (int i = 0; i < 2; ++i) {
      float4 v = src4[i];
      float vv[4] = {v.x, v.y, v.z, v.w};
      bf16x4 hi, lo;
#pragma unroll
      for (int j = 0; j < 4; ++j) {
        unsigned short h = f32_to_bf16(vv[j]);
        hi[j] = (short)h;
        lo[j] = (short)f32_to_bf16(vv[j] - bf16_to_f32(h));
      }
      *(bf16x4*)(xh + r * 72 + f0 + i * 4) = hi;
      *(bf16x4*)(xl + r * 72 + f0 + i * 4) = lo;
    }
  }
  __syncthreads();   // staging visible

  // ---- A fragments, 2 row-tiles: A[m=l16][k=quad*8+j], 32 VGPRs ----
  bf16x8 ah[2][2], al[2][2];
#pragma unroll
  for (int rt = 0; rt < 2; ++rt)
#pragma unroll
    for (int ks = 0; ks < 2; ++ks) {
      ah[rt][ks] = *(const bf16x8*)(xh + (rt * 16 + l16) * 72 + ks * 32 + quad * 8);
      al[rt][ks] = *(const bf16x8*)(xl + (rt * 16 + l16) * 72 + ks * 32 + quad * 8);
    }
  __syncthreads();   // xh/xl dead -> W region writable

  // ---- Phase A: wave's 128-cluster slice x 32 rows, depth-2 prefetch ----
  const int cbase = wv * 128;
  const int bko = quad * 8;
  f32x4 srow[2] = {{0.f,0.f,0.f,0.f},{0.f,0.f,0.f,0.f}};

  bf16x8 pbh0[2], pbh1[2], pbl0[2], pbl1[2];
  float pcs[2];
#pragma unroll
  for (int p = 0; p < 2; ++p) {
    int cl = cbase + p * 16 + l16;
    pbh0[p] = *(const bf16x8*)(chi + cl * 64 + bko);
    pbh1[p] = *(const bf16x8*)(chi + cl * 64 + 32 + bko);
    pbl0[p] = *(const bf16x8*)(clo + cl * 64 + bko);
    pbl1[p] = *(const bf16x8*)(clo + cl * 64 + 32 + bko);
    pcs[p]  = csqs[cl];
  }

#pragma unroll
  for (int t = 0; t < 8; ++t) {
    const int sl = t & 1;
    bf16x8 cbh0 = pbh0[sl], cbh1 = pbh1[sl], cbl0 = pbl0[sl], cbl1 = pbl1[sl];
    float ccs = pcs[sl];
    if (t < 6) {   // prefetch t+2
      int cl = cbase + (t + 2) * 16 + l16;
      pbh0[sl] = *(const bf16x8*)(chi + cl * 64 + bko);
      pbh1[sl] = *(const bf16x8*)(chi + cl * 64 + 32 + bko);
      pbl0[sl] = *(const bf16x8*)(clo + cl * 64 + bko);
      pbl1[sl] = *(const bf16x8*)(clo + cl * 64 + 32 + bko);
      pcs[sl]  = csqs[cl];
    }
    const int c = cbase + t * 16 + l16;
#pragma unroll
    for (int rt = 0; rt < 2; ++rt) {
      f32x4 a = {0.f, 0.f, 0.f, 0.f};
      a = __builtin_amdgcn_mfma_f32_16x16x32_bf16(ah[rt][0], cbh0, a, 0, 0, 0);
      a = __builtin_amdgcn_mfma_f32_16x16x32_bf16(ah[rt][1], cbh1, a, 0, 0, 0);
      a = __builtin_amdgcn_mfma_f32_16x16x32_bf16(ah[rt][0], cbl0, a, 0, 0, 0);
      a = __builtin_amdgcn_mfma_f32_16x16x32_bf16(ah[rt][1], cbl1, a, 0, 0, 0);
      a = __builtin_amdgcn_mfma_f32_16x16x32_bf16(al[rt][0], cbh0, a, 0, 0, 0);
      a = __builtin_amdgcn_mfma_f32_16x16x32_bf16(al[rt][1], cbh1, a, 0, 0, 0);
      // weight = 2^(20*log2e*cross - 10*log2e*|c|^2); row const cancels
#pragma unroll
      for (int r = 0; r < 4; ++r) {
        float e = exp2f(fmaf(28.85390081777927f, a[r], -ccs));
        srow[rt][r] += e;
        int row = rt * 16 + quad * 4 + r;
        W[row * 512 + ((unsigned)c ^ WSWZ(row))] = f32_to_bf16(e);
      }
    }
  }

  // ---- per-wave partial row sums -> LDS ----
#pragma unroll
  for (int d = 1; d < 16; d <<= 1)
#pragma unroll
    for (int rt = 0; rt < 2; ++rt)
#pragma unroll
      for (int r = 0; r < 4; ++r) srow[rt][r] += __shfl_xor(srow[rt][r], d, 64);
  if (l16 == 0) {
#pragma unroll
    for (int rt = 0; rt < 2; ++rt)
#pragma unroll
      for (int r = 0; r < 4; ++r)
        redsum[(rt * 16 + quad * 4 + r) * 4 + wv] = srow[rt][r];
  }
  __syncthreads();   // W + redsum visible to all waves

  // ---- reciprocal row sums (broadcast LDS reads) ----
  float inv[2][4];
#pragma unroll
  for (int rt = 0; rt < 2; ++rt)
#pragma unroll
    for (int r = 0; r < 4; ++r) {
      f32x4 s4 = *(const f32x4*)(redsum + (rt * 16 + quad * 4 + r) * 4);
      inv[rt][r] = __builtin_amdgcn_rcpf((s4[0] + s4[1]) + (s4[2] + s4[3]));
    }

  // ---- Phase C: wave's 16-feature slice, full K=512, hi-c only ----
  const int feat = wv * 16 + l16;
  const unsigned short* cth = cthi + feat * K_CLUSTERS;
  f32x4 oacc[2] = {{0.f,0.f,0.f,0.f},{0.f,0.f,0.f,0.f}};

  bf16x8 qbh[2];
#pragma unroll
  for (int p = 0; p < 2; ++p)
    qbh[p] = *(const bf16x8*)(cth + p * 32 + quad * 8);
#pragma unroll
  for (int ks = 0; ks < 16; ++ks) {
    const int sl = ks & 1;
    bf16x8 bh = qbh[sl];
    if (ks < 14)   // prefetch ks+2
      qbh[sl] = *(const bf16x8*)(cth + (ks + 2) * 32 + quad * 8);
    const int ac = ks * 32 + quad * 8;
#pragma unroll
    for (int rt = 0; rt < 2; ++rt) {
      int arow = rt * 16 + l16;
      bf16x8 aw = *(const bf16x8*)(W + arow * 512 + ((unsigned)ac ^ WSWZ(arow)));
      oacc[rt] = __builtin_amdgcn_mfma_f32_16x16x32_bf16(aw, bh, oacc[rt], 0, 0, 0);
    }
  }

  // ---- epilogue: normalize, store ----
#pragma unroll
  for (int rt = 0; rt < 2; ++rt) {
    float* obase = out + (rowbase + rt * 16) * D_FEAT + feat;
#pragma unroll
    for (int r = 0; r < 4; ++r)
      obase[(quad * 4 + r) * D_FEAT] = oacc[rt][r] * inv[rt][r];
  }
}

extern "C" void kernel_launch(void* const* d_in, const int* in_sizes, int n_in,
                              void* d_out, int out_size, void* d_ws, size_t ws_size,
                              hipStream_t stream) {
  const float* x    = (const float*)d_in[0];
  const float* cent = (const float*)d_in[1];
  float* out        = (float*)d_out;

  unsigned short* chi  = (unsigned short*)d_ws;
  unsigned short* clo  = chi  + K_CLUSTERS * D_FEAT;
  unsigned short* cthi = clo  + K_CLUSTERS * D_FEAT;
  float*          csqs = (float*)(cthi + K_CLUSTERS * D_FEAT);

  kmeans_prep<<<K_CLUSTERS / 4, THREADS, 0, stream>>>(
      cent, chi, clo, cthi, csqs);

  int nrows = in_sizes[0] / D_FEAT;  // 131072
  kmeans_main<<<nrows / ROWS_PER_BLOCK, THREADS, 0, stream>>>(
      x, chi, clo, cthi, csqs, out);
}